// Round 5
// baseline (693.058 us; speedup 1.0000x reference)
//
#include <hip/hip_runtime.h>
#include <float.h>
#include <math.h>

#define NQ 2048
#define NT 100000
#define DIM 512
#define KTOP 5
#define NCAND 16            // screening survivors per query (exact re-rank set)
#define QTILE 128
#define TTILE 128
#define NTPC 13             // t-tiles per chunk
#define NCH 64              // chunk id space; 8 chunks per XCD
#define TBLKS 782           // ceil(NT/128) -> valid 128-row t-tile blocks
#define QBLKS 16            // NQ/128
#define NSUB 3              // t-sub-blocks per chunk (tiles {5,4,4})
#define CV_TBLKS (TBLKS*16) // 12512 convert tasks for T
#define CV_XBLKS ((NQ/128)*16) // 256 convert tasks for x

typedef float f32x4 __attribute__((ext_vector_type(4)));
typedef short s16x8 __attribute__((ext_vector_type(8)));
typedef unsigned int u32;
typedef unsigned short u16;

__device__ __forceinline__ int tsub_start(int ts) { return (13 * ts + 2) / 3; }

__device__ __forceinline__ bool lt_pair(float v1, int i1, float v2, int i2) {
  return v1 < v2 || (v1 == v2 && i1 < i2);
}

// screening insert: plain < (no index tie-break; selection is value-level,
// final ordering is re-established by the exact re-rank)
__device__ __forceinline__ void ins5f(float* tv, int* tix, float sc, int idx) {
  if (sc < tv[4]) {
    tv[4] = sc; tix[4] = idx;
#pragma unroll
    for (int p = 4; p > 0; --p)
      if (tv[p] < tv[p - 1]) {
        float tf = tv[p]; tv[p] = tv[p - 1]; tv[p - 1] = tf;
        int tn = tix[p]; tix[p] = tix[p - 1]; tix[p - 1] = tn;
      }
  }
}

__device__ __forceinline__ void ins5(float* tv, int* tix, float sc, int idx) {
  if (lt_pair(sc, idx, tv[4], tix[4])) {
    tv[4] = sc; tix[4] = idx;
#pragma unroll
    for (int p = 4; p > 0; --p)
      if (lt_pair(tv[p], tix[p], tv[p - 1], tix[p - 1])) {
        float tf = tv[p]; tv[p] = tv[p - 1]; tv[p - 1] = tf;
        int tn = tix[p]; tix[p] = tix[p - 1]; tix[p - 1] = tn;
      }
  }
}

__device__ __forceinline__ void merge5(float* av, int* ai, const float* bv, const int* bi) {
  float nv[5]; int ni[5];
#pragma unroll
  for (int s = 0; s < 5; ++s) {
    if (lt_pair(av[s], ai[s], bv[4 - s], bi[4 - s])) { nv[s] = av[s]; ni[s] = ai[s]; }
    else { nv[s] = bv[4 - s]; ni[s] = bi[4 - s]; }
  }
#pragma unroll
  for (int a = 0; a < 5; ++a)
#pragma unroll
    for (int b = 0; b < 4 - a; ++b)
      if (lt_pair(nv[b + 1], ni[b + 1], nv[b], ni[b])) {
        float tf = nv[b]; nv[b] = nv[b + 1]; nv[b + 1] = tf;
        int tn = ni[b]; ni[b] = ni[b + 1]; ni[b + 1] = tn;
      }
#pragma unroll
  for (int s = 0; s < 5; ++s) { av[s] = nv[s]; ai[s] = ni[s]; }
}

// ---------------- convert: fp32 -> frag-major HI bf16 only (screening) -------
// Screening is single-product bf16: error on d2 ~ +-0.3 absolute vs typical
// order-stat gaps ~5 near the minimum -> exact re-rank of top-16 is safe.
__global__ __launch_bounds__(256) void convert_kernel(
    const float* __restrict__ x, const float* __restrict__ T,
    short* __restrict__ xhi, short* __restrict__ thi,
    float* __restrict__ t2, float* __restrict__ x2) {
  __shared__ short lh[4096];
  const int bid = blockIdx.x;
  const bool isT = bid < CV_TBLKS;
  const int task = isT ? bid : bid - CV_TBLKS;
  const int blk = task >> 4, kbi = task & 15;
  const float* src = isT ? T : x;
  short* dhi = isT ? thi : xhi;
  float* nrm = isT ? t2 : x2;
  const int nsrc = isT ? NT : NQ;

  const int t = threadIdx.x;
  const int rr = t >> 1, half = t & 1;
  const int grow = blk * 128 + rr;
  const int rs = grow < nsrc ? grow : nsrc - 1;
  const float* p = src + (size_t)rs * DIM + kbi * 32 + half * 16;
  f32x4 v[4];
#pragma unroll
  for (int i = 0; i < 4; ++i) v[i] = ((const f32x4*)p)[i];

  float ss = 0.f;
#pragma unroll
  for (int g = 0; g < 2; ++g) {
    s16x8 hv;
#pragma unroll
    for (int e = 0; e < 8; ++e) {
      int i = g * 8 + e;
      float f = v[i >> 2][i & 3];
      ss = fmaf(f, f, ss);
      u32 u = __builtin_bit_cast(u32, f);
      u32 r1 = u + 0x7FFFu + ((u >> 16) & 1u);        // RNE to bf16
      hv[e] = (short)(r1 >> 16);
    }
    // frag unit: tile = rr>>4, quad = half*2+g, m = rr&15
    int unit = (rr >> 4) * 64 + (half * 2 + g) * 16 + (rr & 15);
    *(s16x8*)(lh + unit * 8) = hv;
  }
  ss += __shfl_xor(ss, 1, 64);       // pair (t, t^1) share a row
  if (half == 0 && grow < nsrc) atomicAdd(nrm + grow, ss);

  __syncthreads();
  size_t obase = ((size_t)(blk * 16 + kbi)) * 4096 + t * 16;
  *(s16x8*)(dhi + obase)     = *(const s16x8*)(lh + t * 16);
  *(s16x8*)(dhi + obase + 8) = *(const s16x8*)(lh + t * 16 + 8);
}

// ---------------- stage 1: screening GEMM, SWAPPED operands -----------------
// R4 post-mortem: VALU-bound (73%) on the C-transpose epilogue. Swap MFMA
// operands (A=T-frags rows, B=X-frags cols) so C[m=t][n=q]: each lane owns a
// FIXED q per jj and 16 t-values in registers -> per-lane top-5 on the native
// layout, NO LDS transpose. Per score: fmaf + 1 compare. Invalid t handled
// data-side: t2v=FLT_MAX makes sc round to FLT_MAX (ULP(3.4e38) >> |2 acc|).
// (256,2): 4 persistent top-5 lists (+40 VGPR) don't fit the (256,3) cap 170
// (R1 spill lesson); in a VALU-issue-bound regime 2 waves/SIMD saturate issue.
__global__ __launch_bounds__(256, 2) void knn_mfma(
    const short* __restrict__ xhi, const short* __restrict__ thi,
    const float* __restrict__ t2g,
    float* __restrict__ pvals, u16* __restrict__ pidx16) {
  __shared__ float msv[128 * 5];   // cross-wave (t-half) merge: 2.5 KB
  __shared__ int   msi[128 * 5];   // + 2.5 KB

  const int tid = threadIdx.x;
  const int w = tid >> 6;
  const int l = tid & 63;
  const int bid = blockIdx.x;
  const u32 rest = (u32)bid >> 3;
  const int inner = (int)(rest % 48u);
  const int chunk = (bid & 7) + 8 * (int)(rest / 48u);
  const int qblk = inner & 15;
  const int tsub = inner >> 4;                 // 0..2
  const int tstart = tsub_start(tsub);
  const int tend = tsub_start(tsub + 1);
  const int q0 = qblk * QTILE;
  const int wr = (w >> 1) * 64;    // t-offset within tile
  const int wc = (w & 1) * 64;     // q-offset within tile
  const int arow = wr >> 4;        // T fragment row group
  const int bcol = wc >> 4;        // X fragment col group

  const s16x8* xh8 = (const s16x8*)xhi;
  const s16x8* th8 = (const s16x8*)thi;

  float tv4[4][KTOP]; int tix4[4][KTOP];   // per-jj (per-q) top-5, registers
#pragma unroll
  for (int jj = 0; jj < 4; ++jj)
#pragma unroll
    for (int s = 0; s < KTOP; ++s) { tv4[jj][s] = FLT_MAX; tix4[jj][s] = 0x7FFFFFFF; }

#pragma unroll 1
  for (int tt = tstart; tt < tend; ++tt) {
    const int bblk = chunk * NTPC + tt;
    if (bblk >= TBLKS) continue;   // fully past NT: partials stay FLT_MAX
    const int tbase = bblk * TTILE;
    f32x4 acc[4][4];
#pragma unroll
    for (int i = 0; i < 4; ++i)
#pragma unroll
      for (int j = 0; j < 4; ++j) acc[i][j] = (f32x4){0.f, 0.f, 0.f, 0.f};

    // element offsets (s16x8 units); kbi stride = 512 units (8192 B)
    u32 offA = (u32)(bblk * 16) * 512u + (u32)(arow * 64 + l);  // T (M side)
    u32 offB = (u32)(qblk * 16) * 512u + (u32)(bcol * 64 + l);  // X (N side)
    s16x8 ah[4], bh[4];
#pragma unroll 1
    for (int kbi = 0; kbi < 16; ++kbi) {
#pragma unroll
      for (int i = 0; i < 4; ++i) {
        ah[i] = th8[offA + i * 64];
        bh[i] = xh8[offB + i * 64];
      }
      offA += 512; offB += 512;
      __builtin_amdgcn_s_setprio(1);
#pragma unroll
      for (int j = 0; j < 4; ++j)
#pragma unroll
        for (int i = 0; i < 4; ++i)
          acc[i][j] = __builtin_amdgcn_mfma_f32_16x16x32_bf16(ah[i], bh[j], acc[i][j], 0, 0, 0);
      __builtin_amdgcn_s_setprio(0);
    }

    // epilogue, native layout: lane owns q = wc+jj*16+(l&15); t varies by (i,r)
    const int tg0 = tbase + wr + ((l >> 4) << 2);
    float t2v[16];
#pragma unroll
    for (int i = 0; i < 4; ++i)
#pragma unroll
      for (int r = 0; r < 4; ++r) {
        int t = tg0 + i * 16 + r;
        float vv = t2g[t < NT ? t : NT - 1];
        t2v[i * 4 + r] = t < NT ? vv : FLT_MAX;   // FLT_MAX-2acc rounds to FLT_MAX
      }
#pragma unroll
    for (int jj = 0; jj < 4; ++jj)
#pragma unroll
      for (int i = 0; i < 4; ++i)
#pragma unroll
        for (int r = 0; r < 4; ++r) {
          float sc = fmaf(-2.f, acc[i][jj][r], t2v[i * 4 + r]);
          ins5f(tv4[jj], tix4[jj], sc, tg0 + i * 16 + r);
        }
  }

  // merge the 4 lanes sharing (l&15, jj): butterfly xor 16, 32 (once per block)
#pragma unroll
  for (int jj = 0; jj < 4; ++jj)
#pragma unroll
    for (int d = 16; d <= 32; d <<= 1) {
      float ov[KTOP]; int oi[KTOP];
#pragma unroll
      for (int s = 0; s < KTOP; ++s) {
        ov[s] = __shfl_xor(tv4[jj][s], d, 64);
        oi[s] = __shfl_xor(tix4[jj][s], d, 64);
      }
      merge5(tv4[jj], tix4[jj], ov, oi);
    }

  // cross-wave: waves 2,3 (t-half 1) publish, waves 0,1 consume + write out
  const int blockBase = (chunk * NTPC + tstart) * TTILE;
  if ((w >> 1) && (l >> 4) == 0) {
#pragma unroll
    for (int jj = 0; jj < 4; ++jj) {
      int qr = wc + jj * 16 + l;
#pragma unroll
      for (int s = 0; s < KTOP; ++s) {
        msv[qr * 5 + s] = tv4[jj][s];
        msi[qr * 5 + s] = tix4[jj][s];
      }
    }
  }
  __syncthreads();
  if (!(w >> 1) && (l >> 4) == 0) {
#pragma unroll
    for (int jj = 0; jj < 4; ++jj) {
      int qr = wc + jj * 16 + l;
      float ov[KTOP]; int oi[KTOP];
#pragma unroll
      for (int s = 0; s < KTOP; ++s) { ov[s] = msv[qr * 5 + s]; oi[s] = msi[qr * 5 + s]; }
      merge5(tv4[jj], tix4[jj], ov, oi);
      int q = q0 + qr;
      // u16 local index: block covers <=5 tiles = 640 t's from blockBase.
      // FLT_MAX sentinels carry garbage offsets - value-masked, never selected.
      size_t base = ((size_t)q * (NCH * NSUB) + (chunk * NSUB + tsub)) * KTOP;
#pragma unroll
      for (int s = 0; s < KTOP; ++s) {
        pvals[base + s] = tv4[jj][s];
        pidx16[base + s] = (u16)(tix4[jj][s] - blockBase);
      }
    }
  }
}

// ---------------- merge16: 960 approx partials -> top-16 indices/query ------
// One wave per query. 16 rounds of global argmin via butterfly reduce; the
// owning lane masks the winner. All register arrays statically indexed.
__global__ __launch_bounds__(256) void knn_merge16(
    const float* __restrict__ pvals, const u16* __restrict__ pidx16,
    int* __restrict__ idx16g) {
  const int M = NCH * NSUB * KTOP;  // 960 = 64 lanes x 15
  int q = (blockIdx.x * 256 + threadIdx.x) >> 6;
  int l = threadIdx.x & 63;
  if (q >= NQ) return;
  float v[15]; int ix[15];
  size_t base = (size_t)q * M;
#pragma unroll
  for (int j = 0; j < 15; ++j) {
    int m = j * 64 + l;
    int slot = m / KTOP;                    // candidate slot = chunk*NSUB+tsub
    int ch = slot / NSUB, ts = slot % NSUB;
    int gb = (ch * NTPC + tsub_start(ts)) * TTILE;
    v[j] = pvals[base + m];
    ix[j] = gb + (int)pidx16[base + m];
  }
  int mywin = 0x7FFFFFFF;
#pragma unroll 1
  for (int r = 0; r < NCAND; ++r) {
    float bv = FLT_MAX; int bi = 0x7FFFFFFF;
#pragma unroll
    for (int j = 0; j < 15; ++j)
      if (lt_pair(v[j], ix[j], bv, bi)) { bv = v[j]; bi = ix[j]; }
#pragma unroll
    for (int d = 1; d < 64; d <<= 1) {
      float ov = __shfl_xor(bv, d, 64);
      int oi = __shfl_xor(bi, d, 64);
      if (lt_pair(ov, oi, bv, bi)) { bv = ov; bi = oi; }
    }
    if (l == r) mywin = bi;     // all lanes agree on bi; lane r records it
#pragma unroll
    for (int j = 0; j < 15; ++j)
      if (ix[j] == bi) v[j] = FLT_MAX;      // global idx unique -> safe mask
  }
  if (l < NCAND) idx16g[q * NCAND + l] = mywin;
}

// ---------------- rerank: exact fp32 d2 for 16 cands/query -> final top-5 ---
__global__ __launch_bounds__(256) void knn_rerank(
    const float* __restrict__ x, const float* __restrict__ T,
    const int* __restrict__ idx16g, const int* __restrict__ labels,
    float* __restrict__ out) {
  __shared__ float sd2[4 * NCAND];
  __shared__ int sti[4 * NCAND];
  const int w = threadIdx.x >> 6, l = threadIdx.x & 63;
  const int q = blockIdx.x * 4 + w;
  const int cand = l >> 2, sub = l & 3;
  const int ti = idx16g[q * NCAND + cand];
  const f32x4* tp = (const f32x4*)(T + (size_t)ti * DIM + sub * 128);
  const f32x4* xp = (const f32x4*)(x + (size_t)q * DIM + sub * 128);
  float dot = 0.f, tt = 0.f, xx = 0.f;
#pragma unroll
  for (int i = 0; i < 32; ++i) {
    f32x4 a = xp[i], b = tp[i];
#pragma unroll
    for (int c = 0; c < 4; ++c) {
      dot = fmaf(a[c], b[c], dot);
      tt  = fmaf(b[c], b[c], tt);
      xx  = fmaf(a[c], a[c], xx);
    }
  }
#pragma unroll
  for (int d = 1; d < 4; d <<= 1) {
    dot += __shfl_xor(dot, d, 64);
    tt  += __shfl_xor(tt, d, 64);
    xx  += __shfl_xor(xx, d, 64);
  }
  if (sub == 0) { sd2[w * NCAND + cand] = xx + tt - 2.f * dot; sti[w * NCAND + cand] = ti; }
  __syncthreads();
  if (l == 0) {
    float tv[KTOP]; int tix[KTOP];
#pragma unroll
    for (int s = 0; s < KTOP; ++s) { tv[s] = FLT_MAX; tix[s] = 0x7FFFFFFF; }
#pragma unroll
    for (int c = 0; c < NCAND; ++c) ins5(tv, tix, sd2[w * NCAND + c], sti[w * NCAND + c]);
#pragma unroll
    for (int s = 0; s < KTOP; ++s) {
      float d2 = tv[s] > 0.f ? tv[s] : 0.f;
      out[(size_t)q * KTOP + s] = sqrtf(d2);                          // topk_dists [Q,K]
      out[(size_t)NQ * KTOP + (size_t)q * KTOP + s] = (float)tix[s];  // topk_inds [Q,K]
      out[(size_t)2 * NQ * KTOP + (size_t)s * NQ + q] =
          (float)labels[tix[s]];                                       // pred [K,Q]
    }
  }
}

extern "C" void kernel_launch(void* const* d_in, const int* in_sizes, int n_in,
                              void* d_out, int out_size, void* d_ws, size_t ws_size,
                              hipStream_t stream) {
  const float* x = (const float*)d_in[0];
  const float* T = (const float*)d_in[1];
  const int* labels = (const int*)d_in[2];
  float* out = (float*)d_out;
  char* ws = (char*)d_ws;

  // ws layout (bytes), total ~116.9 MB
  float* t2     = (float*)(ws + 0);             // 400,000
  float* x2     = (float*)(ws + 401408);        // 8,192
  short* xhi    = (short*)(ws + 409600);        // 2,097,152
  short* thi    = (short*)(ws + 2506752);       // 102,498,304 (end 105,005,056)
  float* pvals  = (float*)(ws + 105005056);     // 7,864,320
  u16*   pidx16 = (u16*)(ws + 112869376);       // 3,932,160
  int*   idx16g = (int*)(ws + 116801536);       // 131,072 (end 116,932,608)

  hipMemsetAsync(ws, 0, 409600, stream);        // zero t2/x2 for atomic norms

  convert_kernel<<<CV_TBLKS + CV_XBLKS, 256, 0, stream>>>(
      x, T, xhi, thi, t2, x2);

  knn_mfma<<<QBLKS * NSUB * NCH, 256, 0, stream>>>(
      xhi, thi, t2, pvals, pidx16);

  knn_merge16<<<(NQ * 64 + 255) / 256, 256, 0, stream>>>(pvals, pidx16, idx16g);

  knn_rerank<<<NQ / 4, 256, 0, stream>>>(x, T, idx16g, labels, out);
}